// Round 7
// baseline (179.548 us; speedup 1.0000x reference)
//
#include <hip/hip_runtime.h>
#include <stdint.h>

// Hard voxelization, MI355X. f32x4 points -> f32 concat out:
//   voxels[60000,32,4], coors[60000,3](z,y,x), npv[60000], voxel_num[1].
//
// R6 counters: k_build 47us (VALUBusy 5%, HBM 19% -> latency-bound on one
// dependent CAS chain/thread; WRITE 63MB = ~741K atomics x 64B write-through).
// R7: (1) 2 points/thread in k_build -> two independent CAS chains in flight;
// (2) k_emit writes all 32 rows (zeros beyond m) so k_init shrinks 48->17MB;
// (3) drop partials zero-init (fully overwritten by k_partials).

#define GX 1024
#define GY 1024
#define GZ 40
#define MAXV 60000
#define MAXP 32
#define HBITS 21
#define HSIZE (1u << HBITS)
#define HMASK (HSIZE - 1u)
#define TB 256
#define ITEMS 16
#define TILE (TB * ITEMS)  // 4096
#define EMPTY64 0xFFFFFFFFFFFFFFFFull
#define VIDMARK 0x80000000u

#define OFF_COORS ((size_t)MAXV * MAXP * 4)            // 7,680,000
#define OFF_NPV   (OFF_COORS + (size_t)MAXV * 3)       // 7,860,000
#define OFF_VNUM  (OFF_NPV + (size_t)MAXV)             // 7,920,000

typedef unsigned long long u64;

__device__ __forceinline__ unsigned hashf(int flat) {
    return ((unsigned)flat * 2654435761u) >> (32 - HBITS);
}

// ---- init: hash=EMPTY, cnt2=0, coors region=0 (voxels/npv covered by k_emit) ----
__global__ void k_init(u64* __restrict__ h64, int* __restrict__ cnt2,
                       float* __restrict__ oF) {
    int i = blockIdx.x * blockDim.x + threadIdx.x;
    int stride = gridDim.x * blockDim.x;
    for (int j = i; j < (int)HSIZE; j += stride) h64[j] = EMPTY64;
    for (int j = i; j < MAXV; j += stride) cnt2[j] = 0;
    for (int j = i; j < MAXV * 3; j += stride) oF[OFF_COORS + j] = 0.f;
}

// ---- build helpers ----
__device__ __forceinline__ int voxel_flat(float4 pt) {
    // identical IEEE f32 math to reference
    float fx = floorf((pt.x + 51.2f) / 0.1f);
    float fy = floorf((pt.y + 51.2f) / 0.1f);
    float fz = floorf((pt.z + 5.0f) / 0.2f);
    int cx = (int)fx, cy = (int)fy, cz = (int)fz;
    bool valid = (fx >= 0.f) & (cx < GX) & (fy >= 0.f) & (cy < GY) & (fz >= 0.f) & (cz < GZ);
    return valid ? (cx * GY + cy) * GZ + cz : -1;
}

__device__ __forceinline__ int resolve_probe(u64 cur, u64 want, unsigned slot,
                                             unsigned flat, unsigned p,
                                             u64* __restrict__ h64) {
    for (int probe = 0; probe < 4096; probe++) {         // bounded: hang-proof
        if (cur == EMPTY64) return (int)slot;            // inserted key+rep in one CAS
        if ((unsigned)(cur >> 32) == flat) {             // existing voxel
            if ((unsigned)cur > p)                       // only if we can lower rep
                atomicMin(&h64[slot], want);             // key equal -> compares rep
            return (int)slot;
        }
        slot = (slot + 1u) & HMASK;
        cur = atomicCAS(&h64[slot], EMPTY64, want);
    }
    return -1;                                           // table full: drop (never here)
}

// ---- build: 2 points/thread -> two independent CAS chains for latency hiding ----
__global__ __launch_bounds__(TB) void k_build(const float4* __restrict__ pts, int n,
                                              u64* __restrict__ h64,
                                              int* __restrict__ pslot) {
    int t = threadIdx.x;
    int p0 = blockIdx.x * (TB * 2) + t;
    int p1 = p0 + TB;
    int flat0 = -1, flat1 = -1;
    float4 a, b;
    if (p0 < n) { a = pts[p0]; flat0 = voxel_flat(a); }
    if (p1 < n) { b = pts[p1]; flat1 = voxel_flat(b); }

    u64 want0 = 0, want1 = 0;
    unsigned slot0 = 0, slot1 = 0;
    u64 cur0 = 0, cur1 = 0;
    // issue both first-probe CASes before consuming either result
    if (flat0 >= 0) {
        want0 = ((u64)(unsigned)flat0 << 32) | (unsigned)p0;
        slot0 = hashf(flat0);
        cur0 = atomicCAS(&h64[slot0], EMPTY64, want0);
    }
    if (flat1 >= 0) {
        want1 = ((u64)(unsigned)flat1 << 32) | (unsigned)p1;
        slot1 = hashf(flat1);
        cur1 = atomicCAS(&h64[slot1], EMPTY64, want1);
    }
    if (p0 < n)
        pslot[p0] = (flat0 >= 0)
            ? resolve_probe(cur0, want0, slot0, (unsigned)flat0, (unsigned)p0, h64) : -1;
    if (p1 < n)
        pslot[p1] = (flat1 >= 0)
            ? resolve_probe(cur1, want1, slot1, (unsigned)flat1, (unsigned)p1, h64) : -1;
}

// ---- partials: flag = (rep==p) via ballot -> bitmask + block sums ----
__global__ __launch_bounds__(TB) void k_partials(const int* __restrict__ pslot,
                                                 const u64* __restrict__ h64, int n,
                                                 u64* __restrict__ flagbits,
                                                 int* __restrict__ partials) {
    __shared__ int sh[TB];
    int t = threadIdx.x;
    int base = blockIdx.x * TILE;
    int s = 0;
    #pragma unroll
    for (int j = 0; j < ITEMS; j++) {
        int i = base + j * TB + t;
        int pred = 0;
        if (i < n) {
            int raw = pslot[i];
            if (raw >= 0) pred = ((unsigned)h64[raw] == (unsigned)i);
        }
        u64 m = __ballot(pred);
        if ((t & 63) == 0) flagbits[i >> 6] = m;   // i is 64-aligned at lane 0
        s += pred;
    }
    sh[t] = s;
    __syncthreads();
    for (int off = TB / 2; off > 0; off >>= 1) {
        if (t < off) sh[t] += sh[t + off];
        __syncthreads();
    }
    if (t == 0) partials[blockIdx.x] = sh[0];
}

__global__ __launch_bounds__(1024) void k_scan(int* __restrict__ partials, int nb,
                                               float* __restrict__ oF) {
    __shared__ int sh[1024];
    int t = threadIdx.x;
    int v = (t < nb) ? partials[t] : 0;
    sh[t] = v;
    __syncthreads();
    for (int off = 1; off < 1024; off <<= 1) {
        int add = (t >= off) ? sh[t - off] : 0;
        __syncthreads();
        sh[t] += add;
        __syncthreads();
    }
    if (t < nb) partials[t] = sh[t] - v;  // exclusive block offsets
    if (t == 1023) {
        int total = sh[1023];
        if (total > MAXV) total = MAXV;
        oF[OFF_VNUM] = (float)total;      // voxel_num
    }
}

// ---- assign: vid = prefix rank; coors; overwrite table rep with marked vid ----
__global__ __launch_bounds__(TB) void k_assign(const u64* __restrict__ flagbits,
                                               const int* __restrict__ partials,
                                               const int* __restrict__ pslot,
                                               u64* __restrict__ h64,
                                               float* __restrict__ oF) {
    __shared__ int sh[TB];
    int t = threadIdx.x;
    int base = blockIdx.x * TILE;
    unsigned bits = (unsigned)((flagbits[(base >> 6) + (t >> 2)] >> ((t & 3) * 16)) & 0xFFFFull);
    int s = __popc(bits);
    sh[t] = s;
    __syncthreads();
    for (int off = 1; off < TB; off <<= 1) {
        int add = (t >= off) ? sh[t - off] : 0;
        __syncthreads();
        sh[t] += add;
        __syncthreads();
    }
    int vid = partials[blockIdx.x] + (sh[t] - s);
    int ibase = base + t * ITEMS;
    #pragma unroll
    for (int j = 0; j < ITEMS; j++) {
        if ((bits >> j) & 1) {
            if (vid < MAXV) {
                int slot = pslot[ibase + j];
                u64 v = h64[slot];
                int flat = (int)(v >> 32);
                int zc = flat % GZ;
                int t2 = flat / GZ;
                int yc = t2 % GY;
                int xc = t2 / GY;
                size_t cOff = OFF_COORS + (size_t)vid * 3;
                oF[cOff + 0] = (float)zc;
                oF[cOff + 1] = (float)yc;
                oF[cOff + 2] = (float)xc;
                // rep no longer needed: stash vid (marked) for k_scatter
                h64[slot] = ((u64)(unsigned)flat << 32) | (VIDMARK | (unsigned)vid);
            }
            vid++;
        }
    }
}

__global__ void k_scatter(const int* __restrict__ pslot, const u64* __restrict__ h64,
                          int* __restrict__ cnt2, int* __restrict__ list, int n) {
    int p = blockIdx.x * blockDim.x + threadIdx.x;
    if (p >= n) return;
    int raw = pslot[p];
    if (raw < 0) return;
    unsigned low = (unsigned)h64[raw];
    if (!(low & VIDMARK)) return;          // voxel beyond the 60000 cap
    int vid = (int)(low & 0x7FFFFFFFu);
    int pos = atomicAdd(&cnt2[vid], 1);
    if (pos < MAXP) list[vid * MAXP + pos] = p;
}

// ---- emit: all 32 rows per voxel (zeros beyond m) + npv ----
__global__ void k_emit(const float4* __restrict__ pts, const int* __restrict__ cnt2,
                       const int* __restrict__ list, float4* __restrict__ outVox,
                       float* __restrict__ oF) {
    int vid = blockIdx.x * blockDim.x + threadIdx.x;
    if (vid >= MAXV) return;
    int m = cnt2[vid];
    if (m > MAXP) m = MAXP;
    oF[OFF_NPV + vid] = (float)m;
    const int* lst = &list[vid * MAXP];
    const float4 zero = make_float4(0.f, 0.f, 0.f, 0.f);
    int prev = -1;
    for (int r = 0; r < MAXP; r++) {
        float4 row = zero;
        if (r < m) {                       // ascending original-index order
            int best = 0x7FFFFFFF;
            for (int j = 0; j < m; j++) {
                int v = lst[j];
                if (v > prev && v < best) best = v;
            }
            prev = best;
            row = pts[best];               // bit-exact f32x4 row copy
        }
        outVox[vid * MAXP + r] = row;
    }
}

extern "C" void kernel_launch(void* const* d_in, const int* in_sizes, int n_in,
                              void* d_out, int out_size, void* d_ws, size_t ws_size,
                              hipStream_t stream) {
    int n = in_sizes[0] / 4;                       // 1,200,000
    const float4* pts = (const float4*)d_in[0];

    int tb = 256;
    int nbp = (n + tb - 1) / tb;
    int nbp2 = (n + tb * 2 - 1) / (tb * 2);        // k_build: 2 points/thread
    int nb = (n + TILE - 1) / TILE;                // 293
    int nwords = (nb * TILE) / 64;                 // flagbits words (tile-padded)

    // ws layout, ~28.9 MB
    char* base = (char*)d_ws;
    size_t o = 0;
    int* partials = (int*)(base + o);  o += 4096 * 4;
    int* cnt2     = (int*)(base + o);  o += (size_t)MAXV * 4;
    o = (o + 255) & ~(size_t)255;
    u64* flagbits = (u64*)(base + o);  o += (size_t)nwords * 8;
    o = (o + 255) & ~(size_t)255;
    u64* h64      = (u64*)(base + o);  o += (size_t)HSIZE * 8;
    int* pslot    = (int*)(base + o);  o += (size_t)n * 4;
    int* list     = (int*)(base + o);  o += (size_t)MAXV * MAXP * 4;

    float* oF = (float*)d_out;

    k_init<<<2048, tb, 0, stream>>>(h64, cnt2, oF);
    k_build<<<nbp2, tb, 0, stream>>>(pts, n, h64, pslot);
    k_partials<<<nb, TB, 0, stream>>>(pslot, h64, n, flagbits, partials);
    k_scan<<<1, 1024, 0, stream>>>(partials, nb, oF);
    k_assign<<<nb, TB, 0, stream>>>(flagbits, partials, pslot, h64, oF);
    k_scatter<<<nbp, tb, 0, stream>>>(pslot, h64, cnt2, list, n);
    k_emit<<<(MAXV + tb - 1) / tb, tb, 0, stream>>>(pts, cnt2, list, (float4*)d_out, oF);
}

// Round 8
// 166.301 us; speedup vs baseline: 1.0797x; 1.0797x over previous
//
#include <hip/hip_runtime.h>
#include <stdint.h>

// Hard voxelization, MI355X. f32x4 points -> f32 concat out:
//   voxels[60000,32,4], coors[60000,3](z,y,x), npv[60000], voxel_num[1].
//
// R7 forensics: k_build pinned at 47us by scattered-64B atomic write-through
// (~1.34 TB/s ceiling); ILP didn't help. R8 removes the OTHER two big costs:
//  - flag via build-time "contested" byte array (atomicMin returns old rep ->
//    underminer marks previous holder) => no 44MB random h64 gather in partials.
//  - first-occurrence points self-scatter in k_assign (vid known there;
//    unique writer => non-atomic cnt2=1, list[0]=rep). k_scatter handles only
//    ~6K non-first points (dup rate ~1% at lambda=0.016).

#define GX 1024
#define GY 1024
#define GZ 40
#define MAXV 60000
#define MAXP 32
#define HBITS 21
#define HSIZE (1u << HBITS)
#define HMASK (HSIZE - 1u)
#define CANDBIT (1 << 30)
#define TB 256
#define ITEMS 16
#define TILE (TB * ITEMS)  // 4096
#define EMPTY64 0xFFFFFFFFFFFFFFFFull
#define VIDMARK 0x80000000u

#define OFF_COORS ((size_t)MAXV * MAXP * 4)            // 7,680,000
#define OFF_NPV   (OFF_COORS + (size_t)MAXV * 3)       // 7,860,000
#define OFF_VNUM  (OFF_NPV + (size_t)MAXV)             // 7,920,000

typedef unsigned long long u64;

__device__ __forceinline__ unsigned hashf(int flat) {
    return ((unsigned)flat * 2654435761u) >> (32 - HBITS);
}

// ---- init: hash=EMPTY, cnt2=0, contested=0, coors region=0 ----
__global__ void k_init(u64* __restrict__ h64, int* __restrict__ cnt2,
                       unsigned char* __restrict__ contested, int n,
                       float* __restrict__ oF) {
    int i = blockIdx.x * blockDim.x + threadIdx.x;
    int stride = gridDim.x * blockDim.x;
    for (int j = i; j < (int)HSIZE; j += stride) h64[j] = EMPTY64;
    for (int j = i; j < MAXV; j += stride) cnt2[j] = 0;
    int nw = (n + 3) / 4;
    unsigned* c4 = (unsigned*)contested;
    for (int j = i; j < nw; j += stride) c4[j] = 0;
    for (int j = i; j < MAXV * 3; j += stride) oF[OFF_COORS + j] = 0.f;
}

__device__ __forceinline__ int voxel_flat(float4 pt) {
    // identical IEEE f32 math to reference
    float fx = floorf((pt.x + 51.2f) / 0.1f);
    float fy = floorf((pt.y + 51.2f) / 0.1f);
    float fz = floorf((pt.z + 5.0f) / 0.2f);
    int cx = (int)fx, cy = (int)fy, cz = (int)fz;
    bool valid = (fx >= 0.f) & (cx < GX) & (fy >= 0.f) & (cy < GY) & (fz >= 0.f) & (cz < GZ);
    return valid ? (cx * GY + cy) * GZ + cz : -1;
}

// ---- build: 1 CAS typ.; pslot = slot | CANDBIT(if rep candidate) ----
__global__ __launch_bounds__(TB) void k_build(const float4* __restrict__ pts, int n,
                                              u64* __restrict__ h64,
                                              int* __restrict__ pslot,
                                              unsigned char* __restrict__ contested) {
    int p = blockIdx.x * blockDim.x + threadIdx.x;
    if (p >= n) return;
    float4 pt = pts[p];
    int flat = voxel_flat(pt);
    if (flat < 0) { pslot[p] = -1; return; }
    u64 want = ((u64)(unsigned)flat << 32) | (unsigned)p;
    unsigned slot = hashf(flat);
    int res = -1;
    for (int probe = 0; probe < 4096; probe++) {          // bounded: hang-proof
        u64 cur = atomicCAS(&h64[slot], EMPTY64, want);
        if (cur == EMPTY64) { res = (int)slot | CANDBIT; break; }  // insert winner
        if ((unsigned)(cur >> 32) == (unsigned)flat) {    // existing voxel
            if ((unsigned)cur > (unsigned)p) {
                u64 old = atomicMin(&h64[slot], want);    // key equal -> compares rep
                unsigned oldrep = (unsigned)old;
                if (oldrep > (unsigned)p) {               // we really lowered it
                    contested[oldrep] = 1;                // previous holder dethroned
                    res = (int)slot | CANDBIT;
                } else {
                    res = (int)slot;                      // someone smaller beat us
                }
            } else {
                res = (int)slot;                          // not a candidate
            }
            break;
        }
        slot = (slot + 1u) & HMASK;
    }
    pslot[p] = res;
}

// ---- partials: flag = candidate && !contested (sequential reads only) ----
__global__ __launch_bounds__(TB) void k_partials(const int* __restrict__ pslot,
                                                 const unsigned char* __restrict__ contested,
                                                 int n, u64* __restrict__ flagbits,
                                                 int* __restrict__ partials) {
    __shared__ int sh[TB];
    int t = threadIdx.x;
    int base = blockIdx.x * TILE;
    int s = 0;
    #pragma unroll
    for (int j = 0; j < ITEMS; j++) {
        int i = base + j * TB + t;
        int pred = 0;
        if (i < n) {
            int raw = pslot[i];
            pred = (raw >= 0) && (raw & CANDBIT) && !contested[i];
        }
        u64 m = __ballot(pred);
        if ((t & 63) == 0) flagbits[i >> 6] = m;   // i is 64-aligned at lane 0
        s += pred;
    }
    sh[t] = s;
    __syncthreads();
    for (int off = TB / 2; off > 0; off >>= 1) {
        if (t < off) sh[t] += sh[t + off];
        __syncthreads();
    }
    if (t == 0) partials[blockIdx.x] = sh[0];
}

__global__ __launch_bounds__(1024) void k_scan(int* __restrict__ partials, int nb,
                                               float* __restrict__ oF) {
    __shared__ int sh[1024];
    int t = threadIdx.x;
    int v = (t < nb) ? partials[t] : 0;
    sh[t] = v;
    __syncthreads();
    for (int off = 1; off < 1024; off <<= 1) {
        int add = (t >= off) ? sh[t - off] : 0;
        __syncthreads();
        sh[t] += add;
        __syncthreads();
    }
    if (t < nb) partials[t] = sh[t] - v;  // exclusive block offsets
    if (t == 1023) {
        int total = sh[1023];
        if (total > MAXV) total = MAXV;
        oF[OFF_VNUM] = (float)total;      // voxel_num
    }
}

// ---- assign: vid; coors; self-scatter rep (pos 0, non-atomic); mark vid in h64 ----
__global__ __launch_bounds__(TB) void k_assign(const u64* __restrict__ flagbits,
                                               const int* __restrict__ partials,
                                               const int* __restrict__ pslot,
                                               u64* __restrict__ h64,
                                               int* __restrict__ cnt2,
                                               int* __restrict__ list,
                                               float* __restrict__ oF) {
    __shared__ int sh[TB];
    int t = threadIdx.x;
    int base = blockIdx.x * TILE;
    unsigned bits = (unsigned)((flagbits[(base >> 6) + (t >> 2)] >> ((t & 3) * 16)) & 0xFFFFull);
    int s = __popc(bits);
    sh[t] = s;
    __syncthreads();
    for (int off = 1; off < TB; off <<= 1) {
        int add = (t >= off) ? sh[t - off] : 0;
        __syncthreads();
        sh[t] += add;
        __syncthreads();
    }
    int vid = partials[blockIdx.x] + (sh[t] - s);
    int ibase = base + t * ITEMS;
    #pragma unroll
    for (int j = 0; j < ITEMS; j++) {
        if ((bits >> j) & 1) {
            if (vid < MAXV) {
                int i = ibase + j;
                int slot = pslot[i] & HMASK;
                u64 v = h64[slot];
                int flat = (int)(v >> 32);
                int zc = flat % GZ;
                int t2 = flat / GZ;
                int yc = t2 % GY;
                int xc = t2 / GY;
                size_t cOff = OFF_COORS + (size_t)vid * 3;
                oF[cOff + 0] = (float)zc;
                oF[cOff + 1] = (float)yc;
                oF[cOff + 2] = (float)xc;
                // rep self-scatter: unique writer for this vid
                cnt2[vid] = 1;
                list[vid * MAXP] = i;
                // stash marked vid for k_scatter's (rare) lookups
                h64[slot] = ((u64)(unsigned)flat << 32) | (VIDMARK | (unsigned)vid);
            }
            vid++;
        }
    }
}

// ---- scatter: ONLY non-first points (~6K) do a table lookup + atomic ----
__global__ void k_scatter(const int* __restrict__ pslot,
                          const unsigned char* __restrict__ contested,
                          const u64* __restrict__ h64,
                          int* __restrict__ cnt2, int* __restrict__ list, int n) {
    int p = blockIdx.x * blockDim.x + threadIdx.x;
    if (p >= n) return;
    int raw = pslot[p];
    if (raw < 0) return;
    if ((raw & CANDBIT) && !contested[p]) return;   // first-occurrence: already placed
    unsigned low = (unsigned)h64[raw & HMASK];
    if (!(low & VIDMARK)) return;                   // voxel beyond the 60000 cap
    int vid = (int)(low & 0x7FFFFFFFu);
    int pos = atomicAdd(&cnt2[vid], 1);
    if (pos < MAXP) list[vid * MAXP + pos] = p;
}

// ---- emit: all 32 rows per voxel (zeros beyond m) + npv ----
__global__ void k_emit(const float4* __restrict__ pts, const int* __restrict__ cnt2,
                       const int* __restrict__ list, float4* __restrict__ outVox,
                       float* __restrict__ oF) {
    int vid = blockIdx.x * blockDim.x + threadIdx.x;
    if (vid >= MAXV) return;
    int m = cnt2[vid];
    if (m > MAXP) m = MAXP;
    oF[OFF_NPV + vid] = (float)m;
    const int* lst = &list[vid * MAXP];
    const float4 zero = make_float4(0.f, 0.f, 0.f, 0.f);
    int prev = -1;
    for (int r = 0; r < MAXP; r++) {
        float4 row = zero;
        if (r < m) {                       // ascending original-index order
            int best = 0x7FFFFFFF;
            for (int j = 0; j < m; j++) {
                int v = lst[j];
                if (v > prev && v < best) best = v;
            }
            prev = best;
            row = pts[best];               // bit-exact f32x4 row copy
        }
        outVox[vid * MAXP + r] = row;
    }
}

extern "C" void kernel_launch(void* const* d_in, const int* in_sizes, int n_in,
                              void* d_out, int out_size, void* d_ws, size_t ws_size,
                              hipStream_t stream) {
    int n = in_sizes[0] / 4;                       // 1,200,000
    const float4* pts = (const float4*)d_in[0];

    int tb = 256;
    int nbp = (n + tb - 1) / tb;
    int nb = (n + TILE - 1) / TILE;                // 293
    int nwords = (nb * TILE) / 64;                 // flagbits words (tile-padded)

    // ws layout, ~30 MB
    char* base = (char*)d_ws;
    size_t o = 0;
    int* partials = (int*)(base + o);  o += 4096 * 4;
    int* cnt2     = (int*)(base + o);  o += (size_t)MAXV * 4;
    o = (o + 255) & ~(size_t)255;
    u64* flagbits = (u64*)(base + o);  o += (size_t)nwords * 8;
    o = (o + 255) & ~(size_t)255;
    unsigned char* contested = (unsigned char*)(base + o);  o += ((size_t)n + 255) & ~(size_t)255;
    u64* h64      = (u64*)(base + o);  o += (size_t)HSIZE * 8;
    int* pslot    = (int*)(base + o);  o += (size_t)n * 4;
    int* list     = (int*)(base + o);  o += (size_t)MAXV * MAXP * 4;

    float* oF = (float*)d_out;

    k_init<<<2048, tb, 0, stream>>>(h64, cnt2, contested, n, oF);
    k_build<<<nbp, tb, 0, stream>>>(pts, n, h64, pslot, contested);
    k_partials<<<nb, TB, 0, stream>>>(pslot, contested, n, flagbits, partials);
    k_scan<<<1, 1024, 0, stream>>>(partials, nb, oF);
    k_assign<<<nb, TB, 0, stream>>>(flagbits, partials, pslot, h64, cnt2, list, oF);
    k_scatter<<<nbp, tb, 0, stream>>>(pslot, contested, h64, cnt2, list, n);
    k_emit<<<(MAXV + tb - 1) / tb, tb, 0, stream>>>(pts, cnt2, list, (float4*)d_out, oF);
}